// Round 10
// baseline (375.310 us; speedup 1.0000x reference)
//
#include <hip/hip_runtime.h>

// B=131072, T=16, D=2, H=64. R15: dual-tile ILP.
// Occupancy lever failed 3x (R12/R13/R14: measured occupancy never moved; two
// scratch leaks). New lever: 2 independent 16-row tiles (A,B) per wave,
// interleaved -> 24 chains/CU (vs 16), weight-frag reads shared between tiles,
// epilogue uses all 64 lanes (A: lanes 0-31, B: 32-63). ZERO new dataflow
// patterns: every piece is the R9-proven idiom duplicated with NAMED A/B vars
// (rule-#20 safe), no new barriers, numerics bit-identical to R9 per row.
// LDS: 16384+4096+3072+18432+10240+1024 = 53248 (R12-verified exact)
//   -> 3 blocks/CU; VGPR est ~125, cap 170 (LDS caps residency, so no cliff).
#define BSZ 131072
#define TT  16
#define RPB 128
#define BLK 256

#define NEG_LOG2E  (-1.4426950408889634f)
#define TWO_LOG2E  2.8853900817779268f

typedef __bf16 bf16x8 __attribute__((ext_vector_type(8)));
typedef float  f32x4  __attribute__((ext_vector_type(4)));

#define MFMA(a,b,c) __builtin_amdgcn_mfma_f32_16x16x32_bf16((a),(b),(c),0,0,0)

static __device__ __forceinline__ float rcp_f(float v){ float r; asm("v_rcp_f32 %0, %1" : "=v"(r) : "v"(v)); return r; }
static __device__ __forceinline__ float exp2_f(float v){ float r; asm("v_exp_f32 %0, %1" : "=v"(r) : "v"(v)); return r; }

// one GRU element (R9-exact formulas, scaled domain)
#define GRU_ELEM(SR_IN, SZ_IN, GIN, CN_I, HREF, OUTROW)                        \
  {                                                                            \
    const float r_   = rcp_f(1.0f + exp2_f(SR_IN));                            \
    const float pre_ = fminf(fmaf(r_, CN_I, GIN), 61.f);                       \
    const float Ez_  = exp2_f(SZ_IN);                                          \
    const float En_  = exp2_f(pre_);                                           \
    const float S_   = En_ + 1.0f;                                             \
    const float num_ = fmaf(S_, HREF + Ez_, Ez_ * -2.0f);                      \
    const float den_ = fmaf(S_, Ez_, S_);                                      \
    const float hv_  = num_ * rcp_f(den_);                                     \
    HREF = hv_;                                                                \
    hbuf[(OUTROW)*72 + g*16 + n16] = (__bf16)hv_;                              \
  }

__global__ __launch_bounds__(BLK, 3) void flow15(
    const float* __restrict__ x,     // (B,16,2)
    const float* __restrict__ z,     // (B,64)
    const float* __restrict__ W_ih,  // (192,2)
    const float* __restrict__ W_hh,  // (192,64)
    const float* __restrict__ b_ih,  // (192)
    const float* __restrict__ b_hh,  // (192)
    const float* __restrict__ W1,    // (64,32)
    const float* __restrict__ b1,    // (32)
    const float* __restrict__ W2,    // (32,4)
    const float* __restrict__ b2,    // (4)
    float* __restrict__ y_out,       // (B,16,2)
    float* __restrict__ lad_out)     // (B)
{
  // LDS: 16384 + 4096 + 3072 + 18432 + 10240 + 1024 = 53248 B (3 blocks/CU)
  __shared__ __align__(16) __bf16 whhtab[16*64*8];  // z/n-gate B-frags (pre-scaled)
  __shared__ __align__(16) __bf16 w1tab[4*64*8];    // W1 B-frags
  __shared__ __align__(16) float4 gi_tab[192];      // {Wih0, Wih1, bias, 0} (pre-scaled)
  __shared__ __align__(16) __bf16 hbuf[RPB*72];     // h bf16, 128 rows, stride 72
  __shared__ __align__(16) __bf16 hidbuf[RPB*40];   // hidden, cols 32..39 = ls pad
  __shared__ __align__(16) float  ystate[RPB*2];    // y_{t-1} [row][comp]

  const int tid  = threadIdx.x;
  const int lane = tid & 63, wave = tid >> 6;
  const int quad = lane >> 4, n16 = lane & 15;
  const int gb   = blockIdx.x * RPB;
  const f32x4 zero = {0.f,0.f,0.f,0.f};

  // ---------- one-time staging ----------
  if (tid < 192) {  // gi_tab, pre-scaled (R9-exact)
    const int j = tid;
    const float sc = (j < 128) ? NEG_LOG2E : TWO_LOG2E;
    const float w0 = W_ih[2*j]*sc, w1 = W_ih[2*j+1]*sc;
    const float bi = b_ih[j], bh = b_hh[j];
    gi_tab[j] = make_float4(w0, w1, ((j < 128) ? bi + bh : bi)*sc, 0.f);
  }
  // whhtab: f = (gate-1)*8 + g*2 + kt, gate 1=z (x -log2e), 2=n (x 2log2e)
  #pragma unroll
  for (int i = 0; i < 4; ++i) {
    const int f = i*4 + wave;
    const int gate = 1 + (f >> 3), g = (f >> 1) & 3, kt = f & 1;
    const float sc = (gate == 1) ? NEG_LOG2E : TWO_LOG2E;
    const float* p = W_hh + (size_t)((gate*4 + g)*16 + n16)*64 + kt*32 + quad*8;
    bf16x8 v;
    #pragma unroll
    for (int j = 0; j < 8; ++j) v[j] = (__bf16)(p[j]*sc);
    *(bf16x8*)&whhtab[(f*64 + lane)*8] = v;
  }
  { // w1tab: frag f = c2*2+kt, one per wave
    const int f = wave, c2 = f >> 1, kt = f & 1;
    bf16x8 v;
    #pragma unroll
    for (int j = 0; j < 8; ++j)
      v[j] = (__bf16)W1[(size_t)(kt*32 + quad*8 + j)*32 + c2*16 + n16];
    *(bf16x8*)&w1tab[(f*64 + lane)*8] = v;
  }
  ystate[tid] = 0.f;   // 256 entries = RPB*2 exactly
  #pragma unroll
  for (int r4 = 0; r4 < 8; ++r4) {  // z -> hbuf (bf16), 128 rows
    const int row = (tid >> 4) + r4*16, col = (tid & 15)*4;
    const float4 zv = *(const float4*)&z[(size_t)(gb + row)*64 + col];
    hbuf[row*72 + col+0] = (__bf16)zv.x; hbuf[row*72 + col+1] = (__bf16)zv.y;
    hbuf[row*72 + col+2] = (__bf16)zv.z; hbuf[row*72 + col+3] = (__bf16)zv.w;
  }

  // r-gate B-frags in regs (pre-scaled): 32 VGPR, shared by both tiles
  bf16x8 Whr[4][2];
  #pragma unroll
  for (int g = 0; g < 4; ++g)
    #pragma unroll
    for (int kt = 0; kt < 2; ++kt) {
      const float* p = W_hh + (size_t)(g*16 + n16)*64 + kt*32 + quad*8;
      bf16x8 v;
      #pragma unroll
      for (int j = 0; j < 8; ++j) v[j] = (__bf16)(p[j]*NEG_LOG2E);
      Whr[g][kt] = v;
    }
  bf16x8 W2f;
  #pragma unroll
  for (int j = 0; j < 8; ++j)
    W2f[j] = (n16 < 4) ? (__bf16)W2[(size_t)(quad*8 + j)*4 + n16] : (__bf16)0.f;

  // h state per tile: hstX[g][i] = h[tile_row(quad*4+i)][g*16+n16]
  const int trowA = wave*16 + quad*4;        // tile A local row base
  const int trowB = 64 + trowA;              // tile B local row base
  f32x4 hstA[4], hstB[4];
  #pragma unroll
  for (int g = 0; g < 4; ++g)
    #pragma unroll
    for (int i = 0; i < 4; ++i) {
      hstA[g][i] = z[(size_t)(gb + trowA + i)*64 + g*16 + n16];
      hstB[g][i] = z[(size_t)(gb + trowB + i)*64 + g*16 + n16];
    }
  float bhn[4];
  #pragma unroll
  for (int g = 0; g < 4; ++g) bhn[g] = b_hh[128 + g*16 + n16]*TWO_LOG2E;
  const float b1v0 = b1[n16], b1v1 = b1[16 + n16];
  const float b2ln = (n16 < 4) ? b2[n16] : 0.f;

  __syncthreads();  // only barrier

  const int arowA = wave*16 + n16;
  const int arowB = 64 + arowA;
  bf16x8 a0A = *(const bf16x8*)&hbuf[arowA*72 + quad*8];
  bf16x8 a1A = *(const bf16x8*)&hbuf[arowA*72 + 32 + quad*8];
  bf16x8 a0B = *(const bf16x8*)&hbuf[arowB*72 + quad*8];
  bf16x8 a1B = *(const bf16x8*)&hbuf[arowB*72 + 32 + quad*8];

  // epilogue: ALL 64 lanes. half 0 = tile A (lanes 0-31), half 1 = tile B.
  const int half = lane >> 5;
  const int erl  = lane & 15;
  const int comp = (lane >> 4) & 1;
  const int erow = half*64 + wave*16 + erl;   // local row 0..127
  const float* xp = x + (size_t)(gb + erow)*(TT*2) + comp;
  float*       yp = y_out + (size_t)(gb + erow)*(TT*2) + comp;
  float yc = 0.f, prodS = 1.0f;

  #pragma unroll 1
  for (int t = 0; t < TT; ++t) {
    const float xt = xp[t*2];   // issue global load early (all lanes, own tile)
    float ysA0[4], ysA1[4], ysB0[4], ysB1[4];
    #pragma unroll
    for (int i = 0; i < 4; ++i) {
      const float2 ya = *(const float2*)&ystate[(trowA + i)*2];
      const float2 yb = *(const float2*)&ystate[(trowB + i)*2];
      ysA0[i] = ya.x; ysA1[i] = ya.y;
      ysB0[i] = yb.x; ysB1[i] = yb.y;
    }

    // ---- GRU per col-group g; frag reads SHARED between tiles ----
    #pragma unroll
    for (int g = 0; g < 4; ++g) {
      const bf16x8 bz0 = *(const bf16x8*)&whhtab[((g*2    )*64 + lane)*8];
      const bf16x8 bz1 = *(const bf16x8*)&whhtab[((g*2 + 1)*64 + lane)*8];
      const bf16x8 bn0 = *(const bf16x8*)&whhtab[((8 + g*2    )*64 + lane)*8];
      const bf16x8 bn1 = *(const bf16x8*)&whhtab[((8 + g*2 + 1)*64 + lane)*8];
      const float4 Tr = gi_tab[      g*16 + n16];
      const float4 Tz = gi_tab[ 64 + g*16 + n16];
      const float4 Tn = gi_tab[128 + g*16 + n16];
      const f32x4 cninit = {bhn[g], bhn[g], bhn[g], bhn[g]};

      f32x4 crA = MFMA(a0A, Whr[g][0], zero); crA = MFMA(a1A, Whr[g][1], crA);
      f32x4 crB = MFMA(a0B, Whr[g][0], zero); crB = MFMA(a1B, Whr[g][1], crB);
      f32x4 czA = MFMA(a0A, bz0, zero);       czA = MFMA(a1A, bz1, czA);
      f32x4 czB = MFMA(a0B, bz0, zero);       czB = MFMA(a1B, bz1, czB);
      f32x4 cnA = MFMA(a0A, bn0, cninit);     cnA = MFMA(a1A, bn1, cnA);
      f32x4 cnB = MFMA(a0B, bn0, cninit);     cnB = MFMA(a1B, bn1, cnB);

      #pragma unroll
      for (int i = 0; i < 4; ++i) {
        const float srA  = fmaf(Tr.x, ysA0[i], fmaf(Tr.y, ysA1[i], Tr.z)) + crA[i];
        const float szA  = fminf(fmaf(Tz.x, ysA0[i], fmaf(Tz.y, ysA1[i], Tz.z)) + czA[i], 61.f);
        const float ginA = fmaf(Tn.x, ysA0[i], fmaf(Tn.y, ysA1[i], Tn.z));
        GRU_ELEM(srA, szA, ginA, cnA[i], hstA[g][i], trowA + i);
        const float srB  = fmaf(Tr.x, ysB0[i], fmaf(Tr.y, ysB1[i], Tr.z)) + crB[i];
        const float szB  = fminf(fmaf(Tz.x, ysB0[i], fmaf(Tz.y, ysB1[i], Tz.z)) + czB[i], 61.f);
        const float ginB = fmaf(Tn.x, ysB0[i], fmaf(Tn.y, ysB1[i], Tn.z));
        GRU_ELEM(srB, szB, ginB, cnB[i], hstB[g][i], trowB + i);
      }
    }

    a0A = *(const bf16x8*)&hbuf[arowA*72 + quad*8];
    a1A = *(const bf16x8*)&hbuf[arowA*72 + 32 + quad*8];
    a0B = *(const bf16x8*)&hbuf[arowB*72 + quad*8];
    a1B = *(const bf16x8*)&hbuf[arowB*72 + 32 + quad*8];

    // ---- MLP1 (w1tab reads shared) ----
    #pragma unroll
    for (int c2 = 0; c2 < 2; ++c2) {
      const float bb = c2 ? b1v1 : b1v0;
      const f32x4 binit = {bb, bb, bb, bb};
      const bf16x8 wA = *(const bf16x8*)&w1tab[((c2*2  )*64 + lane)*8];
      const bf16x8 wB = *(const bf16x8*)&w1tab[((c2*2+1)*64 + lane)*8];
      f32x4 hcA = MFMA(a0A, wA, binit); hcA = MFMA(a1A, wB, hcA);
      f32x4 hcB = MFMA(a0B, wA, binit); hcB = MFMA(a1B, wB, hcB);
      #pragma unroll
      for (int i = 0; i < 4; ++i) {
        hidbuf[(trowA + i)*40 + c2*16 + n16] = (__bf16)fmaxf(hcA[i], 0.f);
        hidbuf[(trowB + i)*40 + c2*16 + n16] = (__bf16)fmaxf(hcB[i], 0.f);
      }
    }

    // ---- MLP2: ls -> hidbuf pad (cols 32..39 as 4 floats), both tiles ----
    {
      const bf16x8 haA = *(const bf16x8*)&hidbuf[arowA*40 + quad*8];
      const bf16x8 haB = *(const bf16x8*)&hidbuf[arowB*40 + quad*8];
      const f32x4 b2init = {b2ln, b2ln, b2ln, b2ln};
      const f32x4 lsA = MFMA(haA, W2f, b2init);
      const f32x4 lsB = MFMA(haB, W2f, b2init);
      if (n16 < 4) {
        #pragma unroll
        for (int i = 0; i < 4; ++i) {
          ((float*)&hidbuf[(trowA + i)*40 + 32])[n16] = lsA[i];
          ((float*)&hidbuf[(trowB + i)*40 + 32])[n16] = lsB[i];
        }
      }
    }

    // ---- epilogue: ALL 64 lanes (each lane handles its tile's row/comp) ----
    {
      const float* lsp = (const float*)&hidbuf[erow*40 + 32];
      const float lc = lsp[comp];
      const float l2 = lsp[2 + comp];
      const float s  = __logf(1.0f + __expf(l2)) + 0.001f;
      yc += lc + s * xt;
      prodS *= s;
      ystate[erow*2 + comp] = yc;
      yp[t*2] = yc;
    }
  }

  // logabsdet: combine comp pairs within each 32-lane half
  const float ll  = __logf(prodS);
  const float llo = __shfl(ll, lane ^ 16, 64);
  if ((lane & 16) == 0)
    lad_out[gb + half*64 + wave*16 + (lane & 15)] = ll + llo;
}

extern "C" void kernel_launch(void* const* d_in, const int* in_sizes, int n_in,
                              void* d_out, int out_size, void* d_ws, size_t ws_size,
                              hipStream_t stream) {
  const float* x    = (const float*)d_in[0];
  const float* z    = (const float*)d_in[1];
  const float* W_ih = (const float*)d_in[2];
  const float* W_hh = (const float*)d_in[3];
  const float* b_ih = (const float*)d_in[4];
  const float* b_hh = (const float*)d_in[5];
  const float* W1   = (const float*)d_in[6];
  const float* b1   = (const float*)d_in[7];
  const float* W2   = (const float*)d_in[8];
  const float* b2   = (const float*)d_in[9];

  float* y_out   = (float*)d_out;
  float* lad_out = y_out + (size_t)BSZ * TT * 2;

  dim3 grid(BSZ / RPB), block(BLK);
  hipLaunchKernelGGL(flow15, grid, block, 0, stream,
                     x, z, W_ih, W_hh, b_ih, b_hh, W1, b1, W2, b2,
                     y_out, lad_out);
}

// Round 11
// 251.720 us; speedup vs baseline: 1.4910x; 1.4910x over previous
//
#include <hip/hip_runtime.h>

// B=131072, T=16, D=2, H=64. R16 = R15 dual-tile source + launch_bounds(256,1).
// SESSION KEY FINDING (R15 post-mortem): arch-VGPR cap = 512/(2*min_waves) --
// the backend reserves HALF the budget for the AGPR class:
//   (256,4)->cap 64 (R6: VGPR=64, 2.7GB spill)   (512,6)->cap 42 (R10/11: 40)
//   (256,3)->cap 85 (R5..R15: VGPR=84; spill whenever live>84)
// Every scratch mystery this session was this one rule. R15's dual-tile needs
// ~150-190 arch regs; (256,1) raises the cap to 256 -> fits with margin.
// Occupancy: ~190 total -> 2 waves/SIMD = 8 waves/CU x 2 chains = 16 chains/CU
// (R9-equal) with shared frag reads + full-lane epilogue + 2x per-wave ILP.
// Dual-tile: 2 independent 16-row tiles (A,B) per wave, interleaved; NAMED A/B
// vars (rule-#20 safe); numerics bit-identical to R9 per row (R15: passed).
#define BSZ 131072
#define TT  16
#define RPB 128
#define BLK 256

#define NEG_LOG2E  (-1.4426950408889634f)
#define TWO_LOG2E  2.8853900817779268f

typedef __bf16 bf16x8 __attribute__((ext_vector_type(8)));
typedef float  f32x4  __attribute__((ext_vector_type(4)));

#define MFMA(a,b,c) __builtin_amdgcn_mfma_f32_16x16x32_bf16((a),(b),(c),0,0,0)

static __device__ __forceinline__ float rcp_f(float v){ float r; asm("v_rcp_f32 %0, %1" : "=v"(r) : "v"(v)); return r; }
static __device__ __forceinline__ float exp2_f(float v){ float r; asm("v_exp_f32 %0, %1" : "=v"(r) : "v"(v)); return r; }

// one GRU element (R9-exact formulas, scaled domain)
#define GRU_ELEM(SR_IN, SZ_IN, GIN, CN_I, HREF, OUTROW)                        \
  {                                                                            \
    const float r_   = rcp_f(1.0f + exp2_f(SR_IN));                            \
    const float pre_ = fminf(fmaf(r_, CN_I, GIN), 61.f);                       \
    const float Ez_  = exp2_f(SZ_IN);                                          \
    const float En_  = exp2_f(pre_);                                           \
    const float S_   = En_ + 1.0f;                                             \
    const float num_ = fmaf(S_, HREF + Ez_, Ez_ * -2.0f);                      \
    const float den_ = fmaf(S_, Ez_, S_);                                      \
    const float hv_  = num_ * rcp_f(den_);                                     \
    HREF = hv_;                                                                \
    hbuf[(OUTROW)*72 + g*16 + n16] = (__bf16)hv_;                              \
  }

__global__ __launch_bounds__(BLK, 1) void flow16(
    const float* __restrict__ x,     // (B,16,2)
    const float* __restrict__ z,     // (B,64)
    const float* __restrict__ W_ih,  // (192,2)
    const float* __restrict__ W_hh,  // (192,64)
    const float* __restrict__ b_ih,  // (192)
    const float* __restrict__ b_hh,  // (192)
    const float* __restrict__ W1,    // (64,32)
    const float* __restrict__ b1,    // (32)
    const float* __restrict__ W2,    // (32,4)
    const float* __restrict__ b2,    // (4)
    float* __restrict__ y_out,       // (B,16,2)
    float* __restrict__ lad_out)     // (B)
{
  // LDS: 16384 + 4096 + 3072 + 18432 + 10240 + 1024 = 53248 B
  __shared__ __align__(16) __bf16 whhtab[16*64*8];  // z/n-gate B-frags (pre-scaled)
  __shared__ __align__(16) __bf16 w1tab[4*64*8];    // W1 B-frags
  __shared__ __align__(16) float4 gi_tab[192];      // {Wih0, Wih1, bias, 0} (pre-scaled)
  __shared__ __align__(16) __bf16 hbuf[RPB*72];     // h bf16, 128 rows, stride 72
  __shared__ __align__(16) __bf16 hidbuf[RPB*40];   // hidden, cols 32..39 = ls pad
  __shared__ __align__(16) float  ystate[RPB*2];    // y_{t-1} [row][comp]

  const int tid  = threadIdx.x;
  const int lane = tid & 63, wave = tid >> 6;
  const int quad = lane >> 4, n16 = lane & 15;
  const int gb   = blockIdx.x * RPB;
  const f32x4 zero = {0.f,0.f,0.f,0.f};

  // ---------- one-time staging ----------
  if (tid < 192) {  // gi_tab, pre-scaled (R9-exact)
    const int j = tid;
    const float sc = (j < 128) ? NEG_LOG2E : TWO_LOG2E;
    const float w0 = W_ih[2*j]*sc, w1 = W_ih[2*j+1]*sc;
    const float bi = b_ih[j], bh = b_hh[j];
    gi_tab[j] = make_float4(w0, w1, ((j < 128) ? bi + bh : bi)*sc, 0.f);
  }
  // whhtab: f = (gate-1)*8 + g*2 + kt, gate 1=z (x -log2e), 2=n (x 2log2e)
  #pragma unroll
  for (int i = 0; i < 4; ++i) {
    const int f = i*4 + wave;
    const int gate = 1 + (f >> 3), g = (f >> 1) & 3, kt = f & 1;
    const float sc = (gate == 1) ? NEG_LOG2E : TWO_LOG2E;
    const float* p = W_hh + (size_t)((gate*4 + g)*16 + n16)*64 + kt*32 + quad*8;
    bf16x8 v;
    #pragma unroll
    for (int j = 0; j < 8; ++j) v[j] = (__bf16)(p[j]*sc);
    *(bf16x8*)&whhtab[(f*64 + lane)*8] = v;
  }
  { // w1tab: frag f = c2*2+kt, one per wave
    const int f = wave, c2 = f >> 1, kt = f & 1;
    bf16x8 v;
    #pragma unroll
    for (int j = 0; j < 8; ++j)
      v[j] = (__bf16)W1[(size_t)(kt*32 + quad*8 + j)*32 + c2*16 + n16];
    *(bf16x8*)&w1tab[(f*64 + lane)*8] = v;
  }
  ystate[tid] = 0.f;   // 256 entries = RPB*2 exactly
  #pragma unroll
  for (int r4 = 0; r4 < 8; ++r4) {  // z -> hbuf (bf16), 128 rows
    const int row = (tid >> 4) + r4*16, col = (tid & 15)*4;
    const float4 zv = *(const float4*)&z[(size_t)(gb + row)*64 + col];
    hbuf[row*72 + col+0] = (__bf16)zv.x; hbuf[row*72 + col+1] = (__bf16)zv.y;
    hbuf[row*72 + col+2] = (__bf16)zv.z; hbuf[row*72 + col+3] = (__bf16)zv.w;
  }

  // r-gate B-frags in regs (pre-scaled): 32 VGPR, shared by both tiles
  bf16x8 Whr[4][2];
  #pragma unroll
  for (int g = 0; g < 4; ++g)
    #pragma unroll
    for (int kt = 0; kt < 2; ++kt) {
      const float* p = W_hh + (size_t)(g*16 + n16)*64 + kt*32 + quad*8;
      bf16x8 v;
      #pragma unroll
      for (int j = 0; j < 8; ++j) v[j] = (__bf16)(p[j]*NEG_LOG2E);
      Whr[g][kt] = v;
    }
  bf16x8 W2f;
  #pragma unroll
  for (int j = 0; j < 8; ++j)
    W2f[j] = (n16 < 4) ? (__bf16)W2[(size_t)(quad*8 + j)*4 + n16] : (__bf16)0.f;

  // h state per tile: hstX[g][i] = h[tile_row(quad*4+i)][g*16+n16]
  const int trowA = wave*16 + quad*4;        // tile A local row base
  const int trowB = 64 + trowA;              // tile B local row base
  f32x4 hstA[4], hstB[4];
  #pragma unroll
  for (int g = 0; g < 4; ++g)
    #pragma unroll
    for (int i = 0; i < 4; ++i) {
      hstA[g][i] = z[(size_t)(gb + trowA + i)*64 + g*16 + n16];
      hstB[g][i] = z[(size_t)(gb + trowB + i)*64 + g*16 + n16];
    }
  float bhn[4];
  #pragma unroll
  for (int g = 0; g < 4; ++g) bhn[g] = b_hh[128 + g*16 + n16]*TWO_LOG2E;
  const float b1v0 = b1[n16], b1v1 = b1[16 + n16];
  const float b2ln = (n16 < 4) ? b2[n16] : 0.f;

  __syncthreads();  // only barrier

  const int arowA = wave*16 + n16;
  const int arowB = 64 + arowA;
  bf16x8 a0A = *(const bf16x8*)&hbuf[arowA*72 + quad*8];
  bf16x8 a1A = *(const bf16x8*)&hbuf[arowA*72 + 32 + quad*8];
  bf16x8 a0B = *(const bf16x8*)&hbuf[arowB*72 + quad*8];
  bf16x8 a1B = *(const bf16x8*)&hbuf[arowB*72 + 32 + quad*8];

  // epilogue: ALL 64 lanes. half 0 = tile A (lanes 0-31), half 1 = tile B.
  const int half = lane >> 5;
  const int erl  = lane & 15;
  const int comp = (lane >> 4) & 1;
  const int erow = half*64 + wave*16 + erl;   // local row 0..127
  const float* xp = x + (size_t)(gb + erow)*(TT*2) + comp;
  float*       yp = y_out + (size_t)(gb + erow)*(TT*2) + comp;
  float yc = 0.f, prodS = 1.0f;

  #pragma unroll 1
  for (int t = 0; t < TT; ++t) {
    const float xt = xp[t*2];   // issue global load early (all lanes, own tile)
    float ysA0[4], ysA1[4], ysB0[4], ysB1[4];
    #pragma unroll
    for (int i = 0; i < 4; ++i) {
      const float2 ya = *(const float2*)&ystate[(trowA + i)*2];
      const float2 yb = *(const float2*)&ystate[(trowB + i)*2];
      ysA0[i] = ya.x; ysA1[i] = ya.y;
      ysB0[i] = yb.x; ysB1[i] = yb.y;
    }

    // ---- GRU per col-group g; frag reads SHARED between tiles ----
    #pragma unroll
    for (int g = 0; g < 4; ++g) {
      const bf16x8 bz0 = *(const bf16x8*)&whhtab[((g*2    )*64 + lane)*8];
      const bf16x8 bz1 = *(const bf16x8*)&whhtab[((g*2 + 1)*64 + lane)*8];
      const bf16x8 bn0 = *(const bf16x8*)&whhtab[((8 + g*2    )*64 + lane)*8];
      const bf16x8 bn1 = *(const bf16x8*)&whhtab[((8 + g*2 + 1)*64 + lane)*8];
      const float4 Tr = gi_tab[      g*16 + n16];
      const float4 Tz = gi_tab[ 64 + g*16 + n16];
      const float4 Tn = gi_tab[128 + g*16 + n16];
      const f32x4 cninit = {bhn[g], bhn[g], bhn[g], bhn[g]};

      f32x4 crA = MFMA(a0A, Whr[g][0], zero); crA = MFMA(a1A, Whr[g][1], crA);
      f32x4 crB = MFMA(a0B, Whr[g][0], zero); crB = MFMA(a1B, Whr[g][1], crB);
      f32x4 czA = MFMA(a0A, bz0, zero);       czA = MFMA(a1A, bz1, czA);
      f32x4 czB = MFMA(a0B, bz0, zero);       czB = MFMA(a1B, bz1, czB);
      f32x4 cnA = MFMA(a0A, bn0, cninit);     cnA = MFMA(a1A, bn1, cnA);
      f32x4 cnB = MFMA(a0B, bn0, cninit);     cnB = MFMA(a1B, bn1, cnB);

      #pragma unroll
      for (int i = 0; i < 4; ++i) {
        const float srA  = fmaf(Tr.x, ysA0[i], fmaf(Tr.y, ysA1[i], Tr.z)) + crA[i];
        const float szA  = fminf(fmaf(Tz.x, ysA0[i], fmaf(Tz.y, ysA1[i], Tz.z)) + czA[i], 61.f);
        const float ginA = fmaf(Tn.x, ysA0[i], fmaf(Tn.y, ysA1[i], Tn.z));
        GRU_ELEM(srA, szA, ginA, cnA[i], hstA[g][i], trowA + i);
        const float srB  = fmaf(Tr.x, ysB0[i], fmaf(Tr.y, ysB1[i], Tr.z)) + crB[i];
        const float szB  = fminf(fmaf(Tz.x, ysB0[i], fmaf(Tz.y, ysB1[i], Tz.z)) + czB[i], 61.f);
        const float ginB = fmaf(Tn.x, ysB0[i], fmaf(Tn.y, ysB1[i], Tn.z));
        GRU_ELEM(srB, szB, ginB, cnB[i], hstB[g][i], trowB + i);
      }
    }

    a0A = *(const bf16x8*)&hbuf[arowA*72 + quad*8];
    a1A = *(const bf16x8*)&hbuf[arowA*72 + 32 + quad*8];
    a0B = *(const bf16x8*)&hbuf[arowB*72 + quad*8];
    a1B = *(const bf16x8*)&hbuf[arowB*72 + 32 + quad*8];

    // ---- MLP1 (w1tab reads shared) ----
    #pragma unroll
    for (int c2 = 0; c2 < 2; ++c2) {
      const float bb = c2 ? b1v1 : b1v0;
      const f32x4 binit = {bb, bb, bb, bb};
      const bf16x8 wA = *(const bf16x8*)&w1tab[((c2*2  )*64 + lane)*8];
      const bf16x8 wB = *(const bf16x8*)&w1tab[((c2*2+1)*64 + lane)*8];
      f32x4 hcA = MFMA(a0A, wA, binit); hcA = MFMA(a1A, wB, hcA);
      f32x4 hcB = MFMA(a0B, wA, binit); hcB = MFMA(a1B, wB, hcB);
      #pragma unroll
      for (int i = 0; i < 4; ++i) {
        hidbuf[(trowA + i)*40 + c2*16 + n16] = (__bf16)fmaxf(hcA[i], 0.f);
        hidbuf[(trowB + i)*40 + c2*16 + n16] = (__bf16)fmaxf(hcB[i], 0.f);
      }
    }

    // ---- MLP2: ls -> hidbuf pad (cols 32..39 as 4 floats), both tiles ----
    {
      const bf16x8 haA = *(const bf16x8*)&hidbuf[arowA*40 + quad*8];
      const bf16x8 haB = *(const bf16x8*)&hidbuf[arowB*40 + quad*8];
      const f32x4 b2init = {b2ln, b2ln, b2ln, b2ln};
      const f32x4 lsA = MFMA(haA, W2f, b2init);
      const f32x4 lsB = MFMA(haB, W2f, b2init);
      if (n16 < 4) {
        #pragma unroll
        for (int i = 0; i < 4; ++i) {
          ((float*)&hidbuf[(trowA + i)*40 + 32])[n16] = lsA[i];
          ((float*)&hidbuf[(trowB + i)*40 + 32])[n16] = lsB[i];
        }
      }
    }

    // ---- epilogue: ALL 64 lanes (each lane handles its tile's row/comp) ----
    {
      const float* lsp = (const float*)&hidbuf[erow*40 + 32];
      const float lc = lsp[comp];
      const float l2 = lsp[2 + comp];
      const float s  = __logf(1.0f + __expf(l2)) + 0.001f;
      yc += lc + s * xt;
      prodS *= s;
      ystate[erow*2 + comp] = yc;
      yp[t*2] = yc;
    }
  }

  // logabsdet: combine comp pairs within each 32-lane half
  const float ll  = __logf(prodS);
  const float llo = __shfl(ll, lane ^ 16, 64);
  if ((lane & 16) == 0)
    lad_out[gb + half*64 + wave*16 + (lane & 15)] = ll + llo;
}

extern "C" void kernel_launch(void* const* d_in, const int* in_sizes, int n_in,
                              void* d_out, int out_size, void* d_ws, size_t ws_size,
                              hipStream_t stream) {
  const float* x    = (const float*)d_in[0];
  const float* z    = (const float*)d_in[1];
  const float* W_ih = (const float*)d_in[2];
  const float* W_hh = (const float*)d_in[3];
  const float* b_ih = (const float*)d_in[4];
  const float* b_hh = (const float*)d_in[5];
  const float* W1   = (const float*)d_in[6];
  const float* b1   = (const float*)d_in[7];
  const float* W2   = (const float*)d_in[8];
  const float* b2   = (const float*)d_in[9];

  float* y_out   = (float*)d_out;
  float* lad_out = y_out + (size_t)BSZ * TT * 2;

  dim3 grid(BSZ / RPB), block(BLK);
  hipLaunchKernelGGL(flow16, grid, block, 0, stream,
                     x, z, W_ih, W_hh, b_ih, b_hh, W1, b1, W2, b2,
                     y_out, lad_out);
}